// Round 1
// baseline (329.464 us; speedup 1.0000x reference)
//
#include <hip/hip_runtime.h>

#define B_ 8
#define N_ 2048
#define D_ 64

typedef __attribute__((ext_vector_type(8))) short bf16x8;
typedef __attribute__((ext_vector_type(4))) float f32x4;

__device__ inline unsigned short f32_bf16_rne(float f) {
    unsigned u = __float_as_uint(f);
    u += 0x7fffu + ((u >> 16) & 1u);
    return (unsigned short)(u >> 16);
}

// packed f32x2 -> bf16x2 (RNE), one instruction; no builtin on gfx950 (T12)
__device__ inline unsigned cvt_pk_bf16(float lo, float hi) {
    unsigned r;
    asm("v_cvt_pk_bf16_f32 %0, %1, %2" : "=v"(r) : "v"(lo), "v"(hi));
    return r;
}

// Kernel A: h = feats @ W^T (fp32), a_src reduction, exp tables for the dst side,
// store hT[b][d][j] as bf16. 512 blocks x 256 threads; block = 32 rows of one batch.
__global__ __launch_bounds__(256) void prep_kernel(
    const float* __restrict__ feats, const float* __restrict__ W,
    const float* __restrict__ attn_src, const float* __restrict__ attn_dst,
    unsigned short* __restrict__ hT, float* __restrict__ a_src,
    float* __restrict__ F1, float* __restrict__ F2) {
    __shared__ float w_lds[64 * 65];          // padded: bank = (o+d)%32, conflict-free
    __shared__ float f_lds[32 * 64];
    __shared__ unsigned short hT_lds[64 * 40]; // row stride 40 ushorts = 80B (16B aligned)

    const int t = threadIdx.x;
    const int b = blockIdx.x >> 6;            // 64 row-tiles per batch
    const int rowbase = (blockIdx.x & 63) * 32;

    // cooperative load W (64x64) into padded LDS
#pragma unroll
    for (int k = 0; k < 4; k++) {
        int lin = (k * 256 + t) * 4;
        float4 v = *(const float4*)(W + lin);
        int o = lin >> 6, d = lin & 63;
        float* p = &w_lds[o * 65 + d];
        p[0] = v.x; p[1] = v.y; p[2] = v.z; p[3] = v.w;
    }
    // cooperative load feats tile (32x64), linear layout
#pragma unroll
    for (int k = 0; k < 2; k++) {
        int lin = (k * 256 + t) * 4;
        float4 v = *(const float4*)(feats + (size_t)(b * N_ + rowbase) * D_ + lin);
        float* p = &f_lds[lin];
        p[0] = v.x; p[1] = v.y; p[2] = v.z; p[3] = v.w;
    }
    __syncthreads();

    const int w = t >> 6;     // wave id: rows w*8 .. w*8+7
    const int o = t & 63;     // output channel
    float acc[8] = {0.f, 0.f, 0.f, 0.f, 0.f, 0.f, 0.f, 0.f};
#pragma unroll 8
    for (int d = 0; d < 64; d++) {
        float wv = w_lds[o * 65 + d];
#pragma unroll
        for (int rr = 0; rr < 8; rr++)
            acc[rr] = fmaf(f_lds[(w * 8 + rr) * 64 + d], wv, acc[rr]);
    }
    float as_ = attn_src[o], ad_ = attn_dst[o];
#pragma unroll
    for (int rr = 0; rr < 8; rr++) {
        int row = rowbase + w * 8 + rr;
        float s1 = acc[rr] * as_;
        float s2 = acc[rr] * ad_;
#pragma unroll
        for (int off = 32; off; off >>= 1) {
            s1 += __shfl_xor(s1, off);
            s2 += __shfl_xor(s2, off);
        }
        if (o == 0) {
            a_src[b * N_ + row] = s1;
            F1[b * N_ + row] = __expf(s2);         // exp(a_dst)
            F2[b * N_ + row] = __expf(0.2f * s2);  // exp(0.2*a_dst)
        }
        hT_lds[o * 40 + w * 8 + rr] = f32_bf16_rne(acc[rr]);
    }
    __syncthreads();
    // transposed store: hT[b][d][rowbase..rowbase+32)
    const int d = t >> 2, seg = t & 3;
    uint4 vv = *(const uint4*)(&hT_lds[d * 40 + seg * 8]);
    *(uint4*)(hT + ((size_t)(b * 64 + d) * N_ + rowbase + seg * 8)) = vv;
}

// Kernel B: masked dual-softmax attention via bf16 MFMA.
// Occupancy fix vs previous version: 1024 blocks x 256 threads; each block owns
// 16 rows, its 4 waves each cover a disjoint 512-column j-slice (no barriers in
// the main loop, hT served straight from L2), partials reduced through LDS once.
// Row-rescaled softmax: divide row i by exp(s_i); then p = exp(d_j) for e>=0,
// exp(0.2 d_j)*exp(-0.8 s_i) otherwise — tables F1/F2 precomputed in prep.
// Denominators computed by MFMA against an all-ones B fragment.
__global__ __launch_bounds__(256, 4) void attn_kernel(
    const int* __restrict__ mask_adj, const int* __restrict__ mask_job,
    const int* __restrict__ batch_idxes,
    const unsigned short* __restrict__ hT, const float* __restrict__ a_src,
    const float* __restrict__ F1, const float* __restrict__ F2,
    const float* __restrict__ feats, const float* __restrict__ lambda_params,
    float* __restrict__ out) {
    __shared__ f32x4 redbuf[3][10][64];       // waves 1..3 partial state: 30 KB

    const int t = threadIdx.x;
    const int b = blockIdx.x >> 7;            // 128 row-tiles per batch
    const int rowbase = (blockIdx.x & 127) * 16;
    const int wid = t >> 6, lane = t & 63;
    const int m = lane & 15, q = lane >> 4;
    const int i_a = rowbase + m;              // A-fragment row this lane owns

    int bi = batch_idxes[b];
    bi = (bi < 0) ? 0 : ((bi >= B_) ? (B_ - 1) : bi);
    const int* mA = mask_adj + (size_t)bi * N_ * N_ + (size_t)i_a * N_;
    const int* mJ = mask_job + (size_t)bi * N_ * N_ + (size_t)i_a * N_;

    const float s = a_src[b * N_ + i_a];
    const float cmpT = __expf(-s);            // compare exp(d) >= exp(-s)  <=>  e >= 0
    const float cT = __expf(-0.8f * s);       // exp(0.2e - s) = cT * exp(0.2 d)
    const float* f1p = F1 + b * N_;
    const float* f2p = F2 + b * N_;
    const unsigned short* hTb = hT + (size_t)b * 64 * N_;

    f32x4 accA[4], accJ[4], accZA, accZJ;
    const f32x4 z4 = {0.f, 0.f, 0.f, 0.f};
#pragma unroll
    for (int dd = 0; dd < 4; dd++) { accA[dd] = z4; accJ[dd] = z4; }
    accZA = z4; accZJ = z4;
    bf16x8 ones;
#pragma unroll
    for (int i = 0; i < 8; i++) ones[i] = (short)0x3F80;  // bf16(1.0)

    for (int jt = 0; jt < 4; jt++) {
        const int j0 = wid * 512 + jt * 128;  // this wave's j-slice, tile jt
#pragma unroll
        for (int kk = 0; kk < 4; kk++) {
            const int jl = j0 + kk * 32 + q * 8;  // this lane's 8 k-slots
            int4 a0 = *(const int4*)(mA + jl);
            int4 a1 = *(const int4*)(mA + jl + 4);
            int4 b0 = *(const int4*)(mJ + jl);
            int4 b1 = *(const int4*)(mJ + jl + 4);
            float4 g0 = *(const float4*)(f1p + jl);
            float4 g1 = *(const float4*)(f1p + jl + 4);
            float4 h0 = *(const float4*)(f2p + jl);
            float4 h1 = *(const float4*)(f2p + jl + 4);
            int ma[8] = {a0.x, a0.y, a0.z, a0.w, a1.x, a1.y, a1.z, a1.w};
            int mj[8] = {b0.x, b0.y, b0.z, b0.w, b1.x, b1.y, b1.z, b1.w};
            float f1v[8] = {g0.x, g0.y, g0.z, g0.w, g1.x, g1.y, g1.z, g1.w};
            float f2v[8] = {h0.x, h0.y, h0.z, h0.w, h1.x, h1.y, h1.z, h1.w};

            unsigned ua[4], uj[4];
#pragma unroll
            for (int wp = 0; wp < 4; wp++) {
                float p0 = (f1v[2 * wp] >= cmpT) ? f1v[2 * wp] : cT * f2v[2 * wp];
                float p1 = (f1v[2 * wp + 1] >= cmpT) ? f1v[2 * wp + 1] : cT * f2v[2 * wp + 1];
                float pa0 = (ma[2 * wp] == 1) ? p0 : 0.f;
                float pa1 = (ma[2 * wp + 1] == 1) ? p1 : 0.f;
                float pj0 = (mj[2 * wp] == 1) ? p0 : 0.f;
                float pj1 = (mj[2 * wp + 1] == 1) ? p1 : 0.f;
                ua[wp] = cvt_pk_bf16(pa0, pa1);
                uj[wp] = cvt_pk_bf16(pj0, pj1);
            }
            union { uint4 u; bf16x8 v; } fa_, fj_;
            fa_.u = make_uint4(ua[0], ua[1], ua[2], ua[3]);
            fj_.u = make_uint4(uj[0], uj[1], uj[2], uj[3]);
            bf16x8 fa = fa_.v, fj = fj_.v;

            // softmax denominators ride the MFMA pipe (B = ones)
            accZA = __builtin_amdgcn_mfma_f32_16x16x32_bf16(fa, ones, accZA, 0, 0, 0);
            accZJ = __builtin_amdgcn_mfma_f32_16x16x32_bf16(fj, ones, accZJ, 0, 0, 0);
#pragma unroll
            for (int dd = 0; dd < 4; dd++) {
                // B fragment: col d = dd*16+m, k-slots q*8.. — direct from L2-resident hT
                bf16x8 fb = *(const bf16x8*)(hTb + (size_t)(dd * 16 + m) * N_ + jl);
                accA[dd] = __builtin_amdgcn_mfma_f32_16x16x32_bf16(fa, fb, accA[dd], 0, 0, 0);
                accJ[dd] = __builtin_amdgcn_mfma_f32_16x16x32_bf16(fj, fb, accJ[dd], 0, 0, 0);
            }
        }
    }

    // cross-wave reduction of j-slice partials (40 f32 per lane = 10 f32x4 chunks)
    if (wid) {
#pragma unroll
        for (int c = 0; c < 4; c++) {
            redbuf[wid - 1][c][lane] = accA[c];
            redbuf[wid - 1][4 + c][lane] = accJ[c];
        }
        redbuf[wid - 1][8][lane] = accZA;
        redbuf[wid - 1][9][lane] = accZJ;
    }
    __syncthreads();
    if (wid == 0) {
#pragma unroll
        for (int wv = 0; wv < 3; wv++) {
#pragma unroll
            for (int c = 0; c < 4; c++) {
                accA[c] += redbuf[wv][c][lane];
                accJ[c] += redbuf[wv][4 + c][lane];
            }
            accZA += redbuf[wv][8][lane];
            accZJ += redbuf[wv][9][lane];
        }
        float invA[4], invJ[4];
#pragma unroll
        for (int r = 0; r < 4; r++) {
            invA[r] = 1.f / accZA[r];
            invJ[r] = 1.f / accZJ[r];
        }
#pragma unroll
        for (int dd = 0; dd < 4; dd++) {
            int d = dd * 16 + m;              // C-frag col = lane&15
            float l0 = lambda_params[d * 2];
            float l1 = lambda_params[d * 2 + 1];
            float e0 = __expf(l0), e1 = __expf(l1);
            float inv = 1.f / (e0 + e1);
            float la = e0 * inv, lj = e1 * inv;
#pragma unroll
            for (int r = 0; r < 4; r++) {
                int i = rowbase + q * 4 + r;  // C-frag row = quad*4 + reg
                size_t off = (size_t)(b * N_ + i) * D_ + d;
                out[off] = la * accA[dd][r] * invA[r] + lj * accJ[dd][r] * invJ[r] + feats[off];
            }
        }
    }
}

extern "C" void kernel_launch(void* const* d_in, const int* in_sizes, int n_in,
                              void* d_out, int out_size, void* d_ws, size_t ws_size,
                              hipStream_t stream) {
    const int* mask_adj = (const int*)d_in[0];
    const int* mask_job = (const int*)d_in[1];
    const int* batch_idxes = (const int*)d_in[2];
    const float* feats = (const float*)d_in[3];
    const float* W = (const float*)d_in[4];
    const float* attn_src = (const float*)d_in[5];
    const float* attn_dst = (const float*)d_in[6];
    const float* lambda_params = (const float*)d_in[7];
    float* out = (float*)d_out;

    unsigned short* hT = (unsigned short*)d_ws;                     // B*64*N bf16 = 2 MB
    float* a_src = (float*)((char*)d_ws + (size_t)B_ * 64 * N_ * 2);
    float* F1 = a_src + B_ * N_;
    float* F2 = F1 + B_ * N_;

    prep_kernel<<<B_ * (N_ / 32), 256, 0, stream>>>(feats, W, attn_src, attn_dst,
                                                    hT, a_src, F1, F2);
    attn_kernel<<<B_ * (N_ / 16), 256, 0, stream>>>(mask_adj, mask_job, batch_idxes,
                                                    hT, a_src, F1, F2, feats,
                                                    lambda_params, out);
}

// Round 2
// 312.738 us; speedup vs baseline: 1.0535x; 1.0535x over previous
//
#include <hip/hip_runtime.h>

#define B_ 8
#define N_ 2048
#define D_ 64

typedef __attribute__((ext_vector_type(8))) short bf16x8;
typedef __attribute__((ext_vector_type(4))) float f32x4;

__device__ inline unsigned short f32_bf16_rne(float f) {
    unsigned u = __float_as_uint(f);
    u += 0x7fffu + ((u >> 16) & 1u);
    return (unsigned short)(u >> 16);
}

// packed f32x2 -> bf16x2 (RNE), one instruction; no builtin on gfx950 (T12)
__device__ inline unsigned cvt_pk_bf16(float lo, float hi) {
    unsigned r;
    asm("v_cvt_pk_bf16_f32 %0, %1, %2" : "=v"(r) : "v"(lo), "v"(hi));
    return r;
}

// Kernel A: h = feats @ W^T (fp32), a_src reduction, exp tables for the dst side,
// store hT[b][d][j] as bf16. 512 blocks x 256 threads; block = 32 rows of one batch.
__global__ __launch_bounds__(256) void prep_kernel(
    const float* __restrict__ feats, const float* __restrict__ W,
    const float* __restrict__ attn_src, const float* __restrict__ attn_dst,
    unsigned short* __restrict__ hT, float* __restrict__ a_src,
    float* __restrict__ F1, float* __restrict__ F2) {
    __shared__ float w_lds[64 * 65];          // padded: bank = (o+d)%32, conflict-free
    __shared__ float f_lds[32 * 64];
    __shared__ unsigned short hT_lds[64 * 40]; // row stride 40 ushorts = 80B (16B aligned)

    const int t = threadIdx.x;
    const int b = blockIdx.x >> 6;            // 64 row-tiles per batch
    const int rowbase = (blockIdx.x & 63) * 32;

    // cooperative load W (64x64) into padded LDS
#pragma unroll
    for (int k = 0; k < 4; k++) {
        int lin = (k * 256 + t) * 4;
        float4 v = *(const float4*)(W + lin);
        int o = lin >> 6, d = lin & 63;
        float* p = &w_lds[o * 65 + d];
        p[0] = v.x; p[1] = v.y; p[2] = v.z; p[3] = v.w;
    }
    // cooperative load feats tile (32x64), linear layout
#pragma unroll
    for (int k = 0; k < 2; k++) {
        int lin = (k * 256 + t) * 4;
        float4 v = *(const float4*)(feats + (size_t)(b * N_ + rowbase) * D_ + lin);
        float* p = &f_lds[lin];
        p[0] = v.x; p[1] = v.y; p[2] = v.z; p[3] = v.w;
    }
    __syncthreads();

    const int w = t >> 6;     // wave id: rows w*8 .. w*8+7
    const int o = t & 63;     // output channel
    float acc[8] = {0.f, 0.f, 0.f, 0.f, 0.f, 0.f, 0.f, 0.f};
#pragma unroll 8
    for (int d = 0; d < 64; d++) {
        float wv = w_lds[o * 65 + d];
#pragma unroll
        for (int rr = 0; rr < 8; rr++)
            acc[rr] = fmaf(f_lds[(w * 8 + rr) * 64 + d], wv, acc[rr]);
    }
    float as_ = attn_src[o], ad_ = attn_dst[o];
#pragma unroll
    for (int rr = 0; rr < 8; rr++) {
        int row = rowbase + w * 8 + rr;
        float s1 = acc[rr] * as_;
        float s2 = acc[rr] * ad_;
#pragma unroll
        for (int off = 32; off; off >>= 1) {
            s1 += __shfl_xor(s1, off);
            s2 += __shfl_xor(s2, off);
        }
        if (o == 0) {
            a_src[b * N_ + row] = s1;
            F1[b * N_ + row] = __expf(s2);         // exp(a_dst)
            F2[b * N_ + row] = __expf(0.2f * s2);  // exp(0.2*a_dst)
        }
        hT_lds[o * 40 + w * 8 + rr] = f32_bf16_rne(acc[rr]);
    }
    __syncthreads();
    // transposed store: hT[b][d][rowbase..rowbase+32)
    const int d = t >> 2, seg = t & 3;
    uint4 vv = *(const uint4*)(&hT_lds[d * 40 + seg * 8]);
    *(uint4*)(hT + ((size_t)(b * 64 + d) * N_ + rowbase + seg * 8)) = vv;
}

// Kernel B: masked dual-softmax attention via bf16 MFMA.
// Latency fix vs previous version: the (jt,kk) nest is flattened into 16 steps
// whose addresses are base + compile-time immediate offsets (lane col base =
// wid*512 + st*32 + q*8 advances 128B/step), and the loop is FULLY UNROLLED so
// the scheduler can hoist loads across step boundaries (register pipelining —
// LLVM does not software-pipeline across GPU loop back-edges, which left the
// previous version stalled on every load at VGPR_Count=52, MfmaUtil 3%).
// launch_bounds(256,3) allows ~168 VGPRs of load landing zone.
__global__ __launch_bounds__(256, 3) void attn_kernel(
    const int* __restrict__ mask_adj, const int* __restrict__ mask_job,
    const int* __restrict__ batch_idxes,
    const unsigned short* __restrict__ hT, const float* __restrict__ a_src,
    const float* __restrict__ F1, const float* __restrict__ F2,
    const float* __restrict__ feats, const float* __restrict__ lambda_params,
    float* __restrict__ out) {
    __shared__ f32x4 redbuf[3][10][64];       // waves 1..3 partial state: 30 KB

    const int t = threadIdx.x;
    const int b = blockIdx.x >> 7;            // 128 row-tiles per batch
    const int rowbase = (blockIdx.x & 127) * 16;
    const int wid = t >> 6, lane = t & 63;
    const int m = lane & 15, q = lane >> 4;
    const int i_a = rowbase + m;              // A-fragment row this lane owns

    int bi = batch_idxes[b];
    bi = (bi < 0) ? 0 : ((bi >= B_) ? (B_ - 1) : bi);

    const int jb = wid * 512 + q * 8;         // lane's column base within the row
    const int* mA = mask_adj + ((size_t)bi * N_ + i_a) * N_ + jb;
    const int* mJ = mask_job + ((size_t)bi * N_ + i_a) * N_ + jb;
    const float* f1p = F1 + b * N_ + jb;
    const float* f2p = F2 + b * N_ + jb;
    const unsigned short* hp0 = hT + (size_t)b * 64 * N_ + (size_t)m * N_ + jb;
    const unsigned short* hp1 = hp0 + 16 * N_;
    const unsigned short* hp2 = hp0 + 32 * N_;
    const unsigned short* hp3 = hp0 + 48 * N_;

    const float s = a_src[b * N_ + i_a];
    const float cmpT = __expf(-s);            // exp(d) >= exp(-s)  <=>  e >= 0
    const float cT = __expf(-0.8f * s);       // exp(0.2e - s) = cT * exp(0.2 d)

    f32x4 accA[4], accJ[4], accZA, accZJ;
    const f32x4 z4 = {0.f, 0.f, 0.f, 0.f};
#pragma unroll
    for (int dd = 0; dd < 4; dd++) { accA[dd] = z4; accJ[dd] = z4; }
    accZA = z4; accZJ = z4;
    bf16x8 ones;
#pragma unroll
    for (int i = 0; i < 8; i++) ones[i] = (short)0x3F80;  // bf16(1.0)

#pragma unroll
    for (int st = 0; st < 16; st++) {
        const int off = st * 32;              // 128B/step immediate offsets
        int4 a0 = *(const int4*)(mA + off);
        int4 a1 = *(const int4*)(mA + off + 4);
        int4 b0 = *(const int4*)(mJ + off);
        int4 b1 = *(const int4*)(mJ + off + 4);
        float4 g0 = *(const float4*)(f1p + off);
        float4 g1 = *(const float4*)(f1p + off + 4);
        float4 h0 = *(const float4*)(f2p + off);
        float4 h1 = *(const float4*)(f2p + off + 4);
        bf16x8 fb0 = *(const bf16x8*)(hp0 + off);
        bf16x8 fb1 = *(const bf16x8*)(hp1 + off);
        bf16x8 fb2 = *(const bf16x8*)(hp2 + off);
        bf16x8 fb3 = *(const bf16x8*)(hp3 + off);

        int ma[8] = {a0.x, a0.y, a0.z, a0.w, a1.x, a1.y, a1.z, a1.w};
        int mj[8] = {b0.x, b0.y, b0.z, b0.w, b1.x, b1.y, b1.z, b1.w};
        float f1v[8] = {g0.x, g0.y, g0.z, g0.w, g1.x, g1.y, g1.z, g1.w};
        float f2v[8] = {h0.x, h0.y, h0.z, h0.w, h1.x, h1.y, h1.z, h1.w};

        unsigned ua[4], uj[4];
#pragma unroll
        for (int wp = 0; wp < 4; wp++) {
            float p0 = (f1v[2 * wp] >= cmpT) ? f1v[2 * wp] : cT * f2v[2 * wp];
            float p1 = (f1v[2 * wp + 1] >= cmpT) ? f1v[2 * wp + 1] : cT * f2v[2 * wp + 1];
            float pa0 = (ma[2 * wp] == 1) ? p0 : 0.f;
            float pa1 = (ma[2 * wp + 1] == 1) ? p1 : 0.f;
            float pj0 = (mj[2 * wp] == 1) ? p0 : 0.f;
            float pj1 = (mj[2 * wp + 1] == 1) ? p1 : 0.f;
            ua[wp] = cvt_pk_bf16(pa0, pa1);
            uj[wp] = cvt_pk_bf16(pj0, pj1);
        }
        union { uint4 u; bf16x8 v; } fa_, fj_;
        fa_.u = make_uint4(ua[0], ua[1], ua[2], ua[3]);
        fj_.u = make_uint4(uj[0], uj[1], uj[2], uj[3]);
        bf16x8 fa = fa_.v, fj = fj_.v;

        // softmax denominators ride the MFMA pipe (B = ones)
        accZA = __builtin_amdgcn_mfma_f32_16x16x32_bf16(fa, ones, accZA, 0, 0, 0);
        accZJ = __builtin_amdgcn_mfma_f32_16x16x32_bf16(fj, ones, accZJ, 0, 0, 0);
        accA[0] = __builtin_amdgcn_mfma_f32_16x16x32_bf16(fa, fb0, accA[0], 0, 0, 0);
        accJ[0] = __builtin_amdgcn_mfma_f32_16x16x32_bf16(fj, fb0, accJ[0], 0, 0, 0);
        accA[1] = __builtin_amdgcn_mfma_f32_16x16x32_bf16(fa, fb1, accA[1], 0, 0, 0);
        accJ[1] = __builtin_amdgcn_mfma_f32_16x16x32_bf16(fj, fb1, accJ[1], 0, 0, 0);
        accA[2] = __builtin_amdgcn_mfma_f32_16x16x32_bf16(fa, fb2, accA[2], 0, 0, 0);
        accJ[2] = __builtin_amdgcn_mfma_f32_16x16x32_bf16(fj, fb2, accJ[2], 0, 0, 0);
        accA[3] = __builtin_amdgcn_mfma_f32_16x16x32_bf16(fa, fb3, accA[3], 0, 0, 0);
        accJ[3] = __builtin_amdgcn_mfma_f32_16x16x32_bf16(fj, fb3, accJ[3], 0, 0, 0);
    }

    // cross-wave reduction of j-slice partials (40 f32 per lane = 10 f32x4 chunks)
    if (wid) {
#pragma unroll
        for (int c = 0; c < 4; c++) {
            redbuf[wid - 1][c][lane] = accA[c];
            redbuf[wid - 1][4 + c][lane] = accJ[c];
        }
        redbuf[wid - 1][8][lane] = accZA;
        redbuf[wid - 1][9][lane] = accZJ;
    }
    __syncthreads();
    if (wid == 0) {
#pragma unroll
        for (int wv = 0; wv < 3; wv++) {
#pragma unroll
            for (int c = 0; c < 4; c++) {
                accA[c] += redbuf[wv][c][lane];
                accJ[c] += redbuf[wv][4 + c][lane];
            }
            accZA += redbuf[wv][8][lane];
            accZJ += redbuf[wv][9][lane];
        }
        float invA[4], invJ[4];
#pragma unroll
        for (int r = 0; r < 4; r++) {
            invA[r] = 1.f / accZA[r];
            invJ[r] = 1.f / accZJ[r];
        }
#pragma unroll
        for (int dd = 0; dd < 4; dd++) {
            int d = dd * 16 + m;              // C-frag col = lane&15
            float l0 = lambda_params[d * 2];
            float l1 = lambda_params[d * 2 + 1];
            float e0 = __expf(l0), e1 = __expf(l1);
            float inv = 1.f / (e0 + e1);
            float la = e0 * inv, lj = e1 * inv;
#pragma unroll
            for (int r = 0; r < 4; r++) {
                int i = rowbase + q * 4 + r;  // C-frag row = quad*4 + reg
                size_t off = (size_t)(b * N_ + i) * D_ + d;
                out[off] = la * accA[dd][r] * invA[r] + lj * accJ[dd][r] * invJ[r] + feats[off];
            }
        }
    }
}

extern "C" void kernel_launch(void* const* d_in, const int* in_sizes, int n_in,
                              void* d_out, int out_size, void* d_ws, size_t ws_size,
                              hipStream_t stream) {
    const int* mask_adj = (const int*)d_in[0];
    const int* mask_job = (const int*)d_in[1];
    const int* batch_idxes = (const int*)d_in[2];
    const float* feats = (const float*)d_in[3];
    const float* W = (const float*)d_in[4];
    const float* attn_src = (const float*)d_in[5];
    const float* attn_dst = (const float*)d_in[6];
    const float* lambda_params = (const float*)d_in[7];
    float* out = (float*)d_out;

    unsigned short* hT = (unsigned short*)d_ws;                     // B*64*N bf16 = 2 MB
    float* a_src = (float*)((char*)d_ws + (size_t)B_ * 64 * N_ * 2);
    float* F1 = a_src + B_ * N_;
    float* F2 = F1 + B_ * N_;

    prep_kernel<<<B_ * (N_ / 32), 256, 0, stream>>>(feats, W, attn_src, attn_dst,
                                                    hT, a_src, F1, F2);
    attn_kernel<<<B_ * (N_ / 16), 256, 0, stream>>>(mask_adj, mask_job, batch_idxes,
                                                    hT, a_src, F1, F2, feats,
                                                    lambda_params, out);
}